// Round 9
// baseline (244.244 us; speedup 1.0000x reference)
//
#include <hip/hip_runtime.h>
#include <hip/hip_fp16.h>

#define IN_F 128
#define OUT_F 32
#define R_NODES 128          // dst nodes per bucket (7 bits)
#define BKT_CAP 3072         // Poisson(2046)+23sigma; overflow handled anyway
#define OVF_CAP 4096
#define EPB 6144             // edges per build block -> grid 261 covers 256 CUs
#define MAXNB 1024           // max buckets => n_nodes <= 131072

// ---------------------------------------------------------------------------
// Stage 1: src-degrees + bucket partition, TWO sweeps (round-8 lesson: with
// grid ~= CU count the per-block serial sweep count is the critical path).
// Sweep 1: read edges once, stage pack+bin in LDS, histogram, out_cnt atomic.
// Scan + per-(block,bin) global chunk reservation (round-3 lesson: never
// grid-scatter to shared lines; block-owned chunks only).
// Sweep 2: linear LDS read -> cursor atomic -> direct store into the block's
// reserved chunk (same line set as a sorted flush; order doesn't matter
// because the chunk is XCD-local and time-local).
// in_cnt counts ONLY overflow edges; main in-degree comes from bucket_sort.
// ---------------------------------------------------------------------------
__global__ __launch_bounds__(1024) void build_kernel(
    const int* __restrict__ src, const int* __restrict__ dst,
    int* __restrict__ out_cnt, int* __restrict__ in_cnt,
    int* __restrict__ gcur, unsigned* __restrict__ bkt,
    int* __restrict__ ovf, int* __restrict__ ovf_cnt,
    int n_edges) {

    __shared__ unsigned stage[EPB];         // 24 KB: packed (src<<7)|local
    __shared__ unsigned short binof[EPB];   // 12 KB
    __shared__ int hist[MAXNB];             // 4 KB: count, then cursor
    __shared__ int lbase[MAXNB];            // 4 KB
    __shared__ int gbase[MAXNB];            // 4 KB
    __shared__ int wsum[16];

    int tid = threadIdx.x;
    int e0 = blockIdx.x * EPB;
    int ecnt = min(EPB, n_edges - e0);

    hist[tid] = 0;                          // one bin per thread (MAXNB==1024)
    __syncthreads();

    // sweep 1: load once, stage in LDS, histogram, src-degree atomic
    for (int k = tid; k < ecnt; k += 1024) {
        int e = e0 + k;
        int s = src[e], d = dst[e];
        atomicAdd(&out_cnt[s], 1);
        int bin = d >> 7;
        atomicAdd(&hist[bin], 1);
        stage[k] = ((unsigned)s << 7) | (unsigned)(d & 127);
        binof[k] = (unsigned short)bin;
    }
    __syncthreads();

    // block-wide exclusive scan (1 bin/thread) + global chunk reservation
    int cnt = hist[tid];
    int lane = tid & 63, wid = tid >> 6;
    int scan = cnt;
    for (int off = 1; off < 64; off <<= 1) {
        int v = __shfl_up(scan, off, 64);
        if (lane >= off) scan += v;
    }
    if (lane == 63) wsum[wid] = scan;
    __syncthreads();
    int woff = 0;
    for (int w = 0; w < wid; ++w) woff += wsum[w];
    int excl = woff + scan - cnt;
    lbase[tid] = excl;
    hist[tid]  = excl;                      // becomes insertion cursor
    if (cnt > 0) gbase[tid] = atomicAdd(&gcur[tid], cnt);
    __syncthreads();

    // sweep 2: linear LDS read -> cursor -> direct chunked global store
    for (int k = tid; k < ecnt; k += 1024) {
        unsigned v = stage[k];
        int bin = binof[k];
        int idx = atomicAdd(&hist[bin], 1);
        int gpos = gbase[bin] + (idx - lbase[bin]);
        if (gpos < BKT_CAP) {
            bkt[(size_t)bin * BKT_CAP + gpos] = v;
        } else {
            int d = bin * R_NODES + (int)(v & 127);
            atomicAdd(&in_cnt[d], 1);       // overflow-only in-degree
            int o = atomicAdd(ovf_cnt, 1);
            if (o < OVF_CAP) {
                ovf[2 * o]     = (int)(v >> 7);
                ovf[2 * o + 1] = d;
            }
        }
    }
}

// ---------------------------------------------------------------------------
// Stage 2: per-bucket sort by local dst -> in-place CSR. One block/bucket.
// Int LDS atomics only (round-6 lesson: no fp LDS-atomic streams).
// Exports nodeoff[] (absolute) and ndeg[] per node.
// ---------------------------------------------------------------------------
__global__ __launch_bounds__(512) void bucket_sort(unsigned* __restrict__ bkt,
                                                   const int* __restrict__ gcur,
                                                   int* __restrict__ ndeg,
                                                   int* __restrict__ nodeoff,
                                                   int n_nodes) {
    __shared__ unsigned ent[BKT_CAP];   // 12 KB
    __shared__ unsigned srt[BKT_CAP];   // 12 KB
    __shared__ int hist[R_NODES];
    __shared__ int base[R_NODES];

    int b = blockIdx.x, tid = threadIdx.x;
    int ecnt = min(gcur[b], BKT_CAP);
    unsigned* gb = bkt + (size_t)b * BKT_CAP;

    if (tid < R_NODES) hist[tid] = 0;
    __syncthreads();

    for (int i = tid; i < ecnt; i += 512) {
        unsigned v = gb[i];
        ent[i] = v;
        atomicAdd(&hist[v & 127u], 1);
    }
    __syncthreads();

    // exclusive scan of 128 bins by wave 0 (2 bins/lane)
    if (tid < 64) {
        int a = hist[2 * tid], bb = hist[2 * tid + 1];
        int s = a + bb;
        int sc = s;
        for (int off = 1; off < 64; off <<= 1) {
            int v = __shfl_up(sc, off, 64);
            if (tid >= off) sc += v;
        }
        int excl = sc - s;
        base[2 * tid] = excl;
        base[2 * tid + 1] = excl + a;
    }
    __syncthreads();

    // export CSR meta (before base becomes a cursor)
    int n0 = b * R_NODES;
    if (tid < R_NODES && n0 + tid < n_nodes) {
        ndeg[n0 + tid]    = hist[tid];
        nodeoff[n0 + tid] = b * BKT_CAP + base[tid];
    }
    __syncthreads();

    // reorder: scatter into srt via cursor atomics (int, LDS)
    for (int i = tid; i < ecnt; i += 512) {
        unsigned v = ent[i];
        int p = atomicAdd(&base[v & 127u], 1);
        srt[p] = v >> 7;                 // keep src only
    }
    __syncthreads();

    // coalesced in-place writeback
    for (int i = tid; i < ecnt; i += 512) gb[i] = srt[i];
}

// ---------------------------------------------------------------------------
// Stage 3: tmp(fp16) = (feat * outdeg^-1/2) @ W.  4 rows x 4 cols/thread.
// ---------------------------------------------------------------------------
__global__ __launch_bounds__(256) void linear_kernel(const float* __restrict__ feat,
                                                     const float* __restrict__ weight,
                                                     const int* __restrict__ out_cnt,
                                                     __half* __restrict__ tmp, int n_nodes) {
    __shared__ float w[IN_F * OUT_F];
    {
        const float4* wg = (const float4*)weight;
        float4* wsh = (float4*)w;
        for (int i = threadIdx.x; i < IN_F * OUT_F / 4; i += 256) wsh[i] = wg[i];
    }
    __syncthreads();

    int q  = threadIdx.x >> 3;
    int cg = threadIdx.x & 7;
    int row0 = blockIdx.x * 128 + q * 4;
    if (row0 >= n_nodes) return;
    int rmax = n_nodes - row0;
    if (rmax > 4) rmax = 4;

    const float4* feat4 = (const float4*)feat;
    float4 acc[4];
#pragma unroll
    for (int r = 0; r < 4; ++r) acc[r] = make_float4(0.f, 0.f, 0.f, 0.f);

    for (int k4 = 0; k4 < IN_F / 4; ++k4) {
        float4 wv0 = *(const float4*)&w[(4 * k4 + 0) * OUT_F + 4 * cg];
        float4 wv1 = *(const float4*)&w[(4 * k4 + 1) * OUT_F + 4 * cg];
        float4 wv2 = *(const float4*)&w[(4 * k4 + 2) * OUT_F + 4 * cg];
        float4 wv3 = *(const float4*)&w[(4 * k4 + 3) * OUT_F + 4 * cg];
#pragma unroll
        for (int r = 0; r < 4; ++r) {
            int rr = (r < rmax) ? r : 0;
            float4 f = feat4[(size_t)(row0 + rr) * (IN_F / 4) + k4];
            acc[r].x += f.x * wv0.x + f.y * wv1.x + f.z * wv2.x + f.w * wv3.x;
            acc[r].y += f.x * wv0.y + f.y * wv1.y + f.z * wv2.y + f.w * wv3.y;
            acc[r].z += f.x * wv0.z + f.y * wv1.z + f.z * wv2.z + f.w * wv3.z;
            acc[r].w += f.x * wv0.w + f.y * wv1.w + f.z * wv2.w + f.w * wv3.w;
        }
    }

#pragma unroll
    for (int r = 0; r < 4; ++r) {
        if (r < rmax) {
            float sc = rsqrtf(fmaxf((float)out_cnt[row0 + r], 1.0f));
            union { __half h[4]; uint2 u; } pk;
            pk.h[0] = __float2half(acc[r].x * sc);
            pk.h[1] = __float2half(acc[r].y * sc);
            pk.h[2] = __float2half(acc[r].z * sc);
            pk.h[3] = __float2half(acc[r].w * sc);
            *(uint2*)&tmp[(size_t)(row0 + r) * OUT_F + 4 * cg] = pk.u;
        }
    }
}

// ---------------------------------------------------------------------------
// Stage 4: CSR gather, NO atomics (round-6 lesson). One 32-lane group per
// node; srcs loaded coalesced, broadcast via shfl(width=32); 8 independent
// tmp-row loads in flight; fp32 register sum; one scaled coalesced write.
// ---------------------------------------------------------------------------
__global__ __launch_bounds__(256) void csr_gather(const unsigned* __restrict__ bkt,
                                                  const int* __restrict__ nodeoff,
                                                  const int* __restrict__ ndeg,
                                                  const int* __restrict__ in_cnt,
                                                  const __half* __restrict__ tmp,
                                                  float* __restrict__ out, int n_nodes) {
    int t = blockIdx.x * 256 + threadIdx.x;
    int node = t >> 5;
    int c = t & 31;
    if (node >= n_nodes) return;

    int start = nodeoff[node];
    int cnt = ndeg[node];

    float a0 = 0.f, a1 = 0.f, a2 = 0.f, a3 = 0.f;
    int j = 0;
    while (j < cnt) {
        int chunk = min(cnt - j, 32);
        int sidx = 0;
        if (c < chunk) sidx = (int)bkt[start + j + c];   // coalesced
        int jj = 0;
        for (; jj + 8 <= chunk; jj += 8) {
            int s0 = __shfl(sidx, jj + 0, 32);
            int s1 = __shfl(sidx, jj + 1, 32);
            int s2 = __shfl(sidx, jj + 2, 32);
            int s3 = __shfl(sidx, jj + 3, 32);
            int s4 = __shfl(sidx, jj + 4, 32);
            int s5 = __shfl(sidx, jj + 5, 32);
            int s6 = __shfl(sidx, jj + 6, 32);
            int s7 = __shfl(sidx, jj + 7, 32);
            float v0 = __half2float(tmp[(size_t)s0 * OUT_F + c]);
            float v1 = __half2float(tmp[(size_t)s1 * OUT_F + c]);
            float v2 = __half2float(tmp[(size_t)s2 * OUT_F + c]);
            float v3 = __half2float(tmp[(size_t)s3 * OUT_F + c]);
            float v4 = __half2float(tmp[(size_t)s4 * OUT_F + c]);
            float v5 = __half2float(tmp[(size_t)s5 * OUT_F + c]);
            float v6 = __half2float(tmp[(size_t)s6 * OUT_F + c]);
            float v7 = __half2float(tmp[(size_t)s7 * OUT_F + c]);
            a0 += v0 + v4; a1 += v1 + v5; a2 += v2 + v6; a3 += v3 + v7;
        }
        for (; jj < chunk; ++jj) {
            int s = __shfl(sidx, jj, 32);
            a0 += __half2float(tmp[(size_t)s * OUT_F + c]);
        }
        j += chunk;
    }

    float dg = (float)(cnt + in_cnt[node]);
    float sc = rsqrtf(fmaxf(dg, 1.0f));
    out[(size_t)node * OUT_F + c] = (a0 + a1 + a2 + a3) * sc;
}

// ---------------------------------------------------------------------------
// Stage 4b: overflow edges — expected 0; correctness only.
// ---------------------------------------------------------------------------
__global__ void ovf_kernel(const int* __restrict__ ovf, const int* __restrict__ ovf_cnt,
                           const int* __restrict__ ndeg, const int* __restrict__ in_cnt,
                           const __half* __restrict__ tmp, float* __restrict__ out) {
    int t = blockIdx.x * blockDim.x + threadIdx.x;
    int e = t >> 5, c = t & 31;
    int n = min(*ovf_cnt, OVF_CAP);
    if (e < n) {
        int s = ovf[2 * e], d = ovf[2 * e + 1];
        float scale = rsqrtf(fmaxf((float)(ndeg[d] + in_cnt[d]), 1.0f));
        atomicAdd(&out[(size_t)d * OUT_F + c],
                  __half2float(tmp[(size_t)s * OUT_F + c]) * scale);
    }
}

// ---------------------------------------------------------------------------
// Fallback (ws too small): atomic scatter path.
// ---------------------------------------------------------------------------
__global__ void scatter_kernel(const int* __restrict__ src, const int* __restrict__ dst,
                               const __half* __restrict__ tmp, float* __restrict__ out,
                               int n_edges) {
    long long t = (long long)blockIdx.x * blockDim.x + threadIdx.x;
    int e = (int)(t >> 5);
    int c = (int)(t & (OUT_F - 1));
    if (e < n_edges) {
        atomicAdd(&out[(size_t)dst[e] * OUT_F + c],
                  __half2float(tmp[(size_t)src[e] * OUT_F + c]));
    }
}

__global__ void finalize_kernel(float* __restrict__ out, const int* __restrict__ in_cnt,
                                int n_total) {
    int t = blockIdx.x * blockDim.x + threadIdx.x;
    if (t < n_total) {
        out[t] *= rsqrtf(fmaxf((float)in_cnt[t >> 5], 1.0f));
    }
}

__global__ void degree_kernel(const int* __restrict__ src, const int* __restrict__ dst,
                              int* __restrict__ out_cnt, int* __restrict__ in_cnt,
                              int n_edges) {
    int i = blockIdx.x * blockDim.x + threadIdx.x;
    if (i < n_edges) {
        atomicAdd(&out_cnt[src[i]], 1);
        atomicAdd(&in_cnt[dst[i]], 1);
    }
}

extern "C" void kernel_launch(void* const* d_in, const int* in_sizes, int n_in,
                              void* d_out, int out_size, void* d_ws, size_t ws_size,
                              hipStream_t stream) {
    const float* feat   = (const float*)d_in[0];
    const int*   src    = (const int*)d_in[1];
    const int*   dst    = (const int*)d_in[2];
    const float* weight = (const float*)d_in[3];
    float*       out    = (float*)d_out;

    int n_nodes = in_sizes[0] / IN_F;   // 100000
    int n_edges = in_sizes[1];          // 1600000
    int n_buckets = (n_nodes + R_NODES - 1) / R_NODES;  // 782 (<= MAXNB)

    // ws layout: [out_cnt n][in_cnt n][gcur MAXNB][ovf_cnt 8][ovf 2*CAP]
    //            [bkt nb*BKT_CAP][tmp fp16 n*32][ndeg n][nodeoff n]
    int*      out_cnt = (int*)d_ws;
    int*      in_cnt  = out_cnt + n_nodes;
    int*      gcur    = in_cnt + n_nodes;
    int*      ovf_cnt = gcur + MAXNB;
    int*      ovf     = ovf_cnt + 8;
    unsigned* bkt     = (unsigned*)(ovf + 2 * OVF_CAP);
    __half*   tmp     = (__half*)(bkt + (size_t)n_buckets * BKT_CAP);
    int*      ndeg    = (int*)(tmp + (size_t)n_nodes * OUT_F);
    int*      nodeoff = ndeg + n_nodes;
    size_t    needed  = (char*)(nodeoff + n_nodes) - (char*)d_ws;

    if (ws_size >= needed && n_buckets <= MAXNB) {
        hipMemsetAsync(out_cnt, 0, ((size_t)2 * n_nodes + MAXNB + 8) * sizeof(int), stream);
        build_kernel<<<(n_edges + EPB - 1) / EPB, 1024, 0, stream>>>(
            src, dst, out_cnt, in_cnt, gcur, bkt, ovf, ovf_cnt, n_edges);
        bucket_sort<<<n_buckets, 512, 0, stream>>>(bkt, gcur, ndeg, nodeoff, n_nodes);
        linear_kernel<<<(n_nodes + 127) / 128, 256, 0, stream>>>(
            feat, weight, out_cnt, tmp, n_nodes);
        csr_gather<<<((size_t)n_nodes * 32 + 255) / 256, 256, 0, stream>>>(
            bkt, nodeoff, ndeg, in_cnt, tmp, out, n_nodes);
        ovf_kernel<<<OVF_CAP * 32 / 256, 256, 0, stream>>>(ovf, ovf_cnt, ndeg, in_cnt, tmp, out);
    } else {
        // fallback: atomic scatter
        __half* tmp_fb = (__half*)(ovf + 2 * OVF_CAP);
        hipMemsetAsync(out_cnt, 0, ((size_t)2 * n_nodes + MAXNB + 8) * sizeof(int), stream);
        hipMemsetAsync(d_out, 0, (size_t)out_size * sizeof(float), stream);
        degree_kernel<<<(n_edges + 255) / 256, 256, 0, stream>>>(src, dst, out_cnt, in_cnt, n_edges);
        linear_kernel<<<(n_nodes + 127) / 128, 256, 0, stream>>>(feat, weight, out_cnt, tmp_fb, n_nodes);
        long long st = (long long)n_edges * OUT_F;
        scatter_kernel<<<(int)((st + 255) / 256), 256, 0, stream>>>(src, dst, tmp_fb, out, n_edges);
        finalize_kernel<<<(n_nodes * OUT_F + 255) / 256, 256, 0, stream>>>(out, in_cnt, n_nodes * OUT_F);
    }
}

// Round 10
// 210.717 us; speedup vs baseline: 1.1591x; 1.1591x over previous
//
#include <hip/hip_runtime.h>
#include <hip/hip_fp16.h>

#define IN_F 128
#define OUT_F 32
#define R_NODES 128          // dst nodes per bucket (7 bits)
#define BKT_CAP 3072         // Poisson(2046)+23sigma; overflow handled anyway
#define OVF_CAP 4096
#define EPB 8192             // edges per build sub-block (round-8 proven)
#define MAXNB 1024           // max buckets => n_nodes <= 131072

// ---------------------------------------------------------------------------
// Mega kernel: block-specialized build || linear (they are independent once
// the src-degree scale moves into the gather). Even blockIdx -> build
// sub-block, odd -> linear sub-block, so every CU co-hosts one of each
// (build is 98% stalled on atomics/latency; linear fills the issue slots).
// LDS is a union: build 61.5 KB / linear 16 KB -> 2 blocks/CU.
// ---------------------------------------------------------------------------
struct BuildSmem {
    unsigned sorted[EPB];        // 32 KB
    unsigned short binof[EPB];   // 16 KB
    int hist[MAXNB];             // count, then cursor
    int lbase[MAXNB];
    int gbase[MAXNB];
    int wsum[16];
};
struct LinSmem { float w[IN_F * OUT_F]; };
union MegaSmem { BuildSmem b; LinSmem l; };

__global__ __launch_bounds__(1024) void mega_kernel(
    const int* __restrict__ src, const int* __restrict__ dst,
    const float* __restrict__ feat, const float* __restrict__ weight,
    int* __restrict__ out_cnt, int* __restrict__ in_cnt,
    int* __restrict__ gcur, unsigned* __restrict__ bkt,
    int* __restrict__ ovf, int* __restrict__ ovf_cnt,
    __half* __restrict__ tmp, int n_edges, int n_nodes,
    int n_bbl, int n_lbl) {

    __shared__ MegaSmem sm;
    int tid = threadIdx.x;
    int bid = blockIdx.x;

    // parity interleave: even -> build, odd -> linear (tail: whoever is left)
    int m2 = 2 * min(n_bbl, n_lbl);
    bool is_build;
    int sub;
    if (bid < m2) { is_build = ((bid & 1) == 0); sub = bid >> 1; }
    else          { is_build = (n_bbl > n_lbl);  sub = m2 / 2 + (bid - m2); }

    if (is_build) {
        // ===== round-8 proven 3-sweep build (verbatim) =====
        int e0 = sub * EPB;
        int ecnt = min(EPB, n_edges - e0);

        sm.b.hist[tid] = 0;
        __syncthreads();

        for (int k = tid; k < ecnt; k += 1024) {
            int e = e0 + k;
            int s = src[e], d = dst[e];
            atomicAdd(&out_cnt[s], 1);
            atomicAdd(&sm.b.hist[d >> 7], 1);
        }
        __syncthreads();

        int cnt = sm.b.hist[tid];
        int lane = tid & 63, wid = tid >> 6;
        int scan = cnt;
        for (int off = 1; off < 64; off <<= 1) {
            int v = __shfl_up(scan, off, 64);
            if (lane >= off) scan += v;
        }
        if (lane == 63) sm.b.wsum[wid] = scan;
        __syncthreads();
        int woff = 0;
        for (int w = 0; w < wid; ++w) woff += sm.b.wsum[w];
        int excl = woff + scan - cnt;
        sm.b.lbase[tid] = excl;
        sm.b.hist[tid]  = excl;             // becomes insertion cursor
        if (cnt > 0) sm.b.gbase[tid] = atomicAdd(&gcur[tid], cnt);
        __syncthreads();

        for (int k = tid; k < ecnt; k += 1024) {
            int e = e0 + k;
            int s = src[e], d = dst[e];
            int bin = d >> 7;
            int idx = atomicAdd(&sm.b.hist[bin], 1);
            sm.b.sorted[idx] = ((unsigned)s << 7) | (unsigned)(d & 127);
            sm.b.binof[idx]  = (unsigned short)bin;
        }
        __syncthreads();

        for (int i = tid; i < ecnt; i += 1024) {
            unsigned v = sm.b.sorted[i];
            int bin = sm.b.binof[i];
            int gpos = sm.b.gbase[bin] + (i - sm.b.lbase[bin]);
            if (gpos < BKT_CAP) {
                bkt[(size_t)bin * BKT_CAP + gpos] = v;
            } else {
                int d = bin * R_NODES + (int)(v & 127);
                atomicAdd(&in_cnt[d], 1);   // overflow-only in-degree
                int o = atomicAdd(ovf_cnt, 1);
                if (o < OVF_CAP) {
                    ovf[2 * o]     = (int)(v >> 7);
                    ovf[2 * o + 1] = d;
                }
            }
        }
    } else {
        // ===== linear: tmp(fp16) = feat @ W, UNSCALED (scale in gather) =====
        if (tid < 1024) ((float4*)sm.l.w)[tid] = ((const float4*)weight)[tid];
        __syncthreads();

        int q  = tid >> 3;                  // 0..127 row-quads
        int cg = tid & 7;                   // col group of 4
        int row0 = sub * 512 + q * 4;
        if (row0 >= n_nodes) return;
        int rmax = n_nodes - row0;
        if (rmax > 4) rmax = 4;

        const float4* feat4 = (const float4*)feat;
        float4 acc[4];
#pragma unroll
        for (int r = 0; r < 4; ++r) acc[r] = make_float4(0.f, 0.f, 0.f, 0.f);

        for (int k4 = 0; k4 < IN_F / 4; ++k4) {
            float4 wv0 = *(const float4*)&sm.l.w[(4 * k4 + 0) * OUT_F + 4 * cg];
            float4 wv1 = *(const float4*)&sm.l.w[(4 * k4 + 1) * OUT_F + 4 * cg];
            float4 wv2 = *(const float4*)&sm.l.w[(4 * k4 + 2) * OUT_F + 4 * cg];
            float4 wv3 = *(const float4*)&sm.l.w[(4 * k4 + 3) * OUT_F + 4 * cg];
#pragma unroll
            for (int r = 0; r < 4; ++r) {
                int rr = (r < rmax) ? r : 0;
                float4 f = feat4[(size_t)(row0 + rr) * (IN_F / 4) + k4];
                acc[r].x += f.x * wv0.x + f.y * wv1.x + f.z * wv2.x + f.w * wv3.x;
                acc[r].y += f.x * wv0.y + f.y * wv1.y + f.z * wv2.y + f.w * wv3.y;
                acc[r].z += f.x * wv0.z + f.y * wv1.z + f.z * wv2.z + f.w * wv3.z;
                acc[r].w += f.x * wv0.w + f.y * wv1.w + f.z * wv2.w + f.w * wv3.w;
            }
        }

#pragma unroll
        for (int r = 0; r < 4; ++r) {
            if (r < rmax) {
                union { __half h[4]; uint2 u; } pk;
                pk.h[0] = __float2half(acc[r].x);
                pk.h[1] = __float2half(acc[r].y);
                pk.h[2] = __float2half(acc[r].z);
                pk.h[3] = __float2half(acc[r].w);
                *(uint2*)&tmp[(size_t)(row0 + r) * OUT_F + 4 * cg] = pk.u;
            }
        }
    }
}

// ---------------------------------------------------------------------------
// Fused sort+gather+overflow: one block per 128-node bucket.
// Sort: LDS histogram (int atomics) + wave scan + LDS reorder (src only) —
// never writes sorted data back to global (saves 12.8 MB RW + 2 launches).
// Gather: 16 groups of 32 lanes, 8 nodes/group; edge srcs broadcast-read
// from LDS; 8 independent tmp-row loads in flight; per-edge src scale
// rsqrt(out_cnt[s]) (broadcast L2 load); register fp32 sum; no atomics
// (round-6 lesson). Overflow folded into the per-node loop (novf==0 fast).
// ---------------------------------------------------------------------------
__global__ __launch_bounds__(512) void sortgather_kernel(
    const unsigned* __restrict__ bkt, const int* __restrict__ gcur,
    const int* __restrict__ out_cnt, const int* __restrict__ in_cnt,
    const int* __restrict__ ovf, const int* __restrict__ ovf_cnt,
    const __half* __restrict__ tmp, float* __restrict__ out, int n_nodes) {

    __shared__ unsigned ent[BKT_CAP];   // 12 KB
    __shared__ unsigned srt[BKT_CAP];   // 12 KB (src ids, node-sorted)
    __shared__ int hist[R_NODES];
    __shared__ int base[R_NODES];
    __shared__ int start[R_NODES];

    int b = blockIdx.x, tid = threadIdx.x;
    int ecnt = min(gcur[b], BKT_CAP);
    const unsigned* gb = bkt + (size_t)b * BKT_CAP;

    if (tid < R_NODES) hist[tid] = 0;
    __syncthreads();

    for (int i = tid; i < ecnt; i += 512) {
        unsigned v = gb[i];
        ent[i] = v;
        atomicAdd(&hist[v & 127u], 1);
    }
    __syncthreads();

    if (tid < 64) {                      // scan 128 bins, 2/lane
        int a = hist[2 * tid], bb = hist[2 * tid + 1];
        int s = a + bb;
        int sc = s;
        for (int off = 1; off < 64; off <<= 1) {
            int v = __shfl_up(sc, off, 64);
            if (tid >= off) sc += v;
        }
        int excl = sc - s;
        base[2 * tid] = excl;
        base[2 * tid + 1] = excl + a;
    }
    __syncthreads();
    if (tid < R_NODES) start[tid] = base[tid];
    __syncthreads();

    for (int i = tid; i < ecnt; i += 512) {
        unsigned v = ent[i];
        int p = atomicAdd(&base[v & 127u], 1);
        srt[p] = v >> 7;                 // src only
    }
    __syncthreads();

    int g = tid >> 5;                    // group 0..15
    int c = tid & 31;                    // column
    int n0 = b * R_NODES;
    int novf = min(*ovf_cnt, OVF_CAP);

    for (int ln = g; ln < R_NODES; ln += 16) {
        int node = n0 + ln;
        if (node >= n_nodes) continue;
        int cnt = hist[ln];
        int st  = start[ln];

        float a0 = 0.f, a1 = 0.f, a2 = 0.f, a3 = 0.f;
        int j = 0;
        for (; j + 8 <= cnt; j += 8) {
            int s0 = (int)srt[st + j + 0], s1 = (int)srt[st + j + 1];
            int s2 = (int)srt[st + j + 2], s3 = (int)srt[st + j + 3];
            int s4 = (int)srt[st + j + 4], s5 = (int)srt[st + j + 5];
            int s6 = (int)srt[st + j + 6], s7 = (int)srt[st + j + 7];
            float r0 = rsqrtf(fmaxf((float)out_cnt[s0], 1.f));
            float r1 = rsqrtf(fmaxf((float)out_cnt[s1], 1.f));
            float r2 = rsqrtf(fmaxf((float)out_cnt[s2], 1.f));
            float r3 = rsqrtf(fmaxf((float)out_cnt[s3], 1.f));
            float r4 = rsqrtf(fmaxf((float)out_cnt[s4], 1.f));
            float r5 = rsqrtf(fmaxf((float)out_cnt[s5], 1.f));
            float r6 = rsqrtf(fmaxf((float)out_cnt[s6], 1.f));
            float r7 = rsqrtf(fmaxf((float)out_cnt[s7], 1.f));
            a0 += r0 * __half2float(tmp[(size_t)s0 * OUT_F + c]);
            a1 += r1 * __half2float(tmp[(size_t)s1 * OUT_F + c]);
            a2 += r2 * __half2float(tmp[(size_t)s2 * OUT_F + c]);
            a3 += r3 * __half2float(tmp[(size_t)s3 * OUT_F + c]);
            a0 += r4 * __half2float(tmp[(size_t)s4 * OUT_F + c]);
            a1 += r5 * __half2float(tmp[(size_t)s5 * OUT_F + c]);
            a2 += r6 * __half2float(tmp[(size_t)s6 * OUT_F + c]);
            a3 += r7 * __half2float(tmp[(size_t)s7 * OUT_F + c]);
        }
        for (; j < cnt; ++j) {
            int s = (int)srt[st + j];
            float r = rsqrtf(fmaxf((float)out_cnt[s], 1.f));
            a0 += r * __half2float(tmp[(size_t)s * OUT_F + c]);
        }
        // overflow fold (novf is ~always 0)
        for (int e2 = 0; e2 < novf; ++e2) {
            if (ovf[2 * e2 + 1] == node) {
                int s = ovf[2 * e2];
                float r = rsqrtf(fmaxf((float)out_cnt[s], 1.f));
                a0 += r * __half2float(tmp[(size_t)s * OUT_F + c]);
            }
        }

        float dg = (float)(cnt + in_cnt[node]);
        float sc = rsqrtf(fmaxf(dg, 1.0f));
        out[(size_t)node * OUT_F + c] = (a0 + a1 + a2 + a3) * sc;
    }
}

// ---------------------------------------------------------------------------
// Fallback path (ws too small): degree + scaled-linear + atomic scatter.
// ---------------------------------------------------------------------------
__global__ void degree_kernel(const int* __restrict__ src, const int* __restrict__ dst,
                              int* __restrict__ out_cnt, int* __restrict__ in_cnt,
                              int n_edges) {
    int i = blockIdx.x * blockDim.x + threadIdx.x;
    if (i < n_edges) {
        atomicAdd(&out_cnt[src[i]], 1);
        atomicAdd(&in_cnt[dst[i]], 1);
    }
}

__global__ __launch_bounds__(256) void linear_fb(const float* __restrict__ feat,
                                                 const float* __restrict__ weight,
                                                 const int* __restrict__ out_cnt,
                                                 __half* __restrict__ tmp, int n_nodes) {
    __shared__ float w[IN_F * OUT_F];
    {
        const float4* wg = (const float4*)weight;
        float4* wsh = (float4*)w;
        for (int i = threadIdx.x; i < IN_F * OUT_F / 4; i += 256) wsh[i] = wg[i];
    }
    __syncthreads();
    int q  = threadIdx.x >> 3;
    int cg = threadIdx.x & 7;
    int row0 = blockIdx.x * 128 + q * 4;
    if (row0 >= n_nodes) return;
    int rmax = n_nodes - row0;
    if (rmax > 4) rmax = 4;
    const float4* feat4 = (const float4*)feat;
    float4 acc[4];
#pragma unroll
    for (int r = 0; r < 4; ++r) acc[r] = make_float4(0.f, 0.f, 0.f, 0.f);
    for (int k4 = 0; k4 < IN_F / 4; ++k4) {
        float4 wv0 = *(const float4*)&w[(4 * k4 + 0) * OUT_F + 4 * cg];
        float4 wv1 = *(const float4*)&w[(4 * k4 + 1) * OUT_F + 4 * cg];
        float4 wv2 = *(const float4*)&w[(4 * k4 + 2) * OUT_F + 4 * cg];
        float4 wv3 = *(const float4*)&w[(4 * k4 + 3) * OUT_F + 4 * cg];
#pragma unroll
        for (int r = 0; r < 4; ++r) {
            int rr = (r < rmax) ? r : 0;
            float4 f = feat4[(size_t)(row0 + rr) * (IN_F / 4) + k4];
            acc[r].x += f.x * wv0.x + f.y * wv1.x + f.z * wv2.x + f.w * wv3.x;
            acc[r].y += f.x * wv0.y + f.y * wv1.y + f.z * wv2.y + f.w * wv3.y;
            acc[r].z += f.x * wv0.z + f.y * wv1.z + f.z * wv2.z + f.w * wv3.z;
            acc[r].w += f.x * wv0.w + f.y * wv1.w + f.z * wv2.w + f.w * wv3.w;
        }
    }
#pragma unroll
    for (int r = 0; r < 4; ++r) {
        if (r < rmax) {
            float sc = rsqrtf(fmaxf((float)out_cnt[row0 + r], 1.0f));
            union { __half h[4]; uint2 u; } pk;
            pk.h[0] = __float2half(acc[r].x * sc);
            pk.h[1] = __float2half(acc[r].y * sc);
            pk.h[2] = __float2half(acc[r].z * sc);
            pk.h[3] = __float2half(acc[r].w * sc);
            *(uint2*)&tmp[(size_t)(row0 + r) * OUT_F + 4 * cg] = pk.u;
        }
    }
}

__global__ void scatter_kernel(const int* __restrict__ src, const int* __restrict__ dst,
                               const __half* __restrict__ tmp, float* __restrict__ out,
                               int n_edges) {
    long long t = (long long)blockIdx.x * blockDim.x + threadIdx.x;
    int e = (int)(t >> 5);
    int c = (int)(t & (OUT_F - 1));
    if (e < n_edges) {
        atomicAdd(&out[(size_t)dst[e] * OUT_F + c],
                  __half2float(tmp[(size_t)src[e] * OUT_F + c]));
    }
}

__global__ void finalize_kernel(float* __restrict__ out, const int* __restrict__ in_cnt,
                                int n_total) {
    int t = blockIdx.x * blockDim.x + threadIdx.x;
    if (t < n_total) {
        out[t] *= rsqrtf(fmaxf((float)in_cnt[t >> 5], 1.0f));
    }
}

extern "C" void kernel_launch(void* const* d_in, const int* in_sizes, int n_in,
                              void* d_out, int out_size, void* d_ws, size_t ws_size,
                              hipStream_t stream) {
    const float* feat   = (const float*)d_in[0];
    const int*   src    = (const int*)d_in[1];
    const int*   dst    = (const int*)d_in[2];
    const float* weight = (const float*)d_in[3];
    float*       out    = (float*)d_out;

    int n_nodes = in_sizes[0] / IN_F;   // 100000
    int n_edges = in_sizes[1];          // 1600000
    int n_buckets = (n_nodes + R_NODES - 1) / R_NODES;  // 782 (<= MAXNB)

    // ws layout: [out_cnt n][in_cnt n][gcur MAXNB][ovf_cnt 8][ovf 2*CAP]
    //            [bkt nb*BKT_CAP][tmp fp16 n*32]
    int*      out_cnt = (int*)d_ws;
    int*      in_cnt  = out_cnt + n_nodes;
    int*      gcur    = in_cnt + n_nodes;
    int*      ovf_cnt = gcur + MAXNB;
    int*      ovf     = ovf_cnt + 8;
    unsigned* bkt     = (unsigned*)(ovf + 2 * OVF_CAP);
    __half*   tmp     = (__half*)(bkt + (size_t)n_buckets * BKT_CAP);
    size_t    needed  = (char*)(tmp + (size_t)n_nodes * OUT_F) - (char*)d_ws;

    if (ws_size >= needed && n_buckets <= MAXNB) {
        hipMemsetAsync(out_cnt, 0, ((size_t)2 * n_nodes + MAXNB + 8) * sizeof(int), stream);
        int n_bbl = (n_edges + EPB - 1) / EPB;          // 196
        int n_lbl = (n_nodes + 511) / 512;              // 196
        mega_kernel<<<n_bbl + n_lbl, 1024, 0, stream>>>(
            src, dst, feat, weight, out_cnt, in_cnt, gcur, bkt, ovf, ovf_cnt,
            tmp, n_edges, n_nodes, n_bbl, n_lbl);
        sortgather_kernel<<<n_buckets, 512, 0, stream>>>(
            bkt, gcur, out_cnt, in_cnt, ovf, ovf_cnt, tmp, out, n_nodes);
    } else {
        // fallback: atomic scatter
        __half* tmp_fb = (__half*)(ovf + 2 * OVF_CAP);
        hipMemsetAsync(out_cnt, 0, ((size_t)2 * n_nodes + MAXNB + 8) * sizeof(int), stream);
        hipMemsetAsync(d_out, 0, (size_t)out_size * sizeof(float), stream);
        degree_kernel<<<(n_edges + 255) / 256, 256, 0, stream>>>(src, dst, out_cnt, in_cnt, n_edges);
        linear_fb<<<(n_nodes + 127) / 128, 256, 0, stream>>>(feat, weight, out_cnt, tmp_fb, n_nodes);
        long long st = (long long)n_edges * OUT_F;
        scatter_kernel<<<(int)((st + 255) / 256), 256, 0, stream>>>(src, dst, tmp_fb, out, n_edges);
        finalize_kernel<<<(n_nodes * OUT_F + 255) / 256, 256, 0, stream>>>(out, in_cnt, n_nodes * OUT_F);
    }
}

// Round 11
// 207.602 us; speedup vs baseline: 1.1765x; 1.0150x over previous
//
#include <hip/hip_runtime.h>
#include <hip/hip_fp16.h>

#define IN_F 128
#define OUT_F 32
#define R_NODES 256          // dst nodes per bucket (8 bits)
#define RSHIFT 8
#define RMASK 255
#define BKT_CAP 7168         // Poisson(4092) + chunk padding (~5720 exp) + 9+ sigma
#define OVF_CAP 4096
#define EPB 8192             // edges per build sub-block (round-8 proven)
#define MAXNB 512            // max buckets => n_nodes <= 131072
#define SENT 0xFFFFFFFFu     // pad sentinel in bkt (skipped by sortgather)

// ---------------------------------------------------------------------------
// Mega kernel: block-specialized build || linear (round-10 proven overlap).
// Build: 3-sweep block-local counting sort. NEW: each (block,bin) chunk is
// reserved ROUNDED UP to 16 entries (one 64B line) -> every bkt line is
// written whole by exactly one block (kills the 64->~10MB partial-line
// amplification; round-3/9 lesson). Holes = SENT, skipped downstream.
// Linear: unscaled feat @ W -> fp16 tmp (src scale folded in later by
// scale_tmp, so linear needs no out_cnt dependency and can overlap build).
// ---------------------------------------------------------------------------
struct BuildSmem {
    unsigned sorted[EPB];        // 32 KB
    unsigned short binof[EPB];   // 16 KB
    int hist[MAXNB];             // count, then cursor
    int lbase[MAXNB];
    int gbase[MAXNB];
    int wsum[16];
};
struct LinSmem { float w[IN_F * OUT_F]; };
union MegaSmem { BuildSmem b; LinSmem l; };

__global__ __launch_bounds__(1024) void mega_kernel(
    const int* __restrict__ src, const int* __restrict__ dst,
    const float* __restrict__ feat, const float* __restrict__ weight,
    int* __restrict__ out_cnt, int* __restrict__ in_cnt,
    int* __restrict__ gcur, unsigned* __restrict__ bkt,
    int* __restrict__ ovf, int* __restrict__ ovf_cnt,
    __half* __restrict__ tmp, int n_edges, int n_nodes,
    int n_bbl, int n_lbl) {

    __shared__ MegaSmem sm;
    int tid = threadIdx.x;
    int bid = blockIdx.x;

    // parity interleave: even -> build, odd -> linear (tail: whoever is left)
    int m2 = 2 * min(n_bbl, n_lbl);
    bool is_build;
    int sub;
    if (bid < m2) { is_build = ((bid & 1) == 0); sub = bid >> 1; }
    else          { is_build = (n_bbl > n_lbl);  sub = m2 / 2 + (bid - m2); }

    if (is_build) {
        int e0 = sub * EPB;
        int ecnt = min(EPB, n_edges - e0);

        if (tid < MAXNB) sm.b.hist[tid] = 0;
        __syncthreads();

        // sweep 1: src-degree atomics + bin histogram
        for (int k = tid; k < ecnt; k += 1024) {
            int e = e0 + k;
            int s = src[e], d = dst[e];
            atomicAdd(&out_cnt[s], 1);
            atomicAdd(&sm.b.hist[d >> RSHIFT], 1);
        }
        __syncthreads();

        // block scan (tid>=MAXNB contribute 0) + LINE-ALIGNED chunk reserve
        int cnt = (tid < MAXNB) ? sm.b.hist[tid] : 0;
        int lane = tid & 63, wid = tid >> 6;
        int scan = cnt;
        for (int off = 1; off < 64; off <<= 1) {
            int v = __shfl_up(scan, off, 64);
            if (lane >= off) scan += v;
        }
        if (lane == 63) sm.b.wsum[wid] = scan;
        __syncthreads();
        int woff = 0;
        for (int w = 0; w < wid; ++w) woff += sm.b.wsum[w];
        int excl = woff + scan - cnt;
        if (tid < MAXNB) {
            sm.b.lbase[tid] = excl;
            sm.b.hist[tid]  = excl;         // becomes insertion cursor
            int res = (cnt + 15) & ~15;     // whole 64B lines
            if (cnt > 0) sm.b.gbase[tid] = atomicAdd(&gcur[tid], res);
        }
        __syncthreads();

        // sweep 2: local counting-sort into LDS
        for (int k = tid; k < ecnt; k += 1024) {
            int e = e0 + k;
            int s = src[e], d = dst[e];
            int bin = d >> RSHIFT;
            int idx = atomicAdd(&sm.b.hist[bin], 1);
            sm.b.sorted[idx] = ((unsigned)s << RSHIFT) | (unsigned)(d & RMASK);
            sm.b.binof[idx]  = (unsigned short)bin;
        }
        __syncthreads();

        // sweep 3: dense line-aligned flush + sentinel pad fill
        for (int i = tid; i < ecnt; i += 1024) {
            unsigned v = sm.b.sorted[i];
            int bin = sm.b.binof[i];
            int gpos = sm.b.gbase[bin] + (i - sm.b.lbase[bin]);
            if (gpos < BKT_CAP) {
                bkt[(size_t)bin * BKT_CAP + gpos] = v;
            } else {
                int d = bin * R_NODES + (int)(v & RMASK);
                atomicAdd(&in_cnt[d], 1);   // overflow-only in-degree
                int o = atomicAdd(ovf_cnt, 1);
                if (o < OVF_CAP) {
                    ovf[2 * o]     = (int)(v >> RSHIFT);
                    ovf[2 * o + 1] = d;
                }
            }
        }
        for (int bin = tid; bin < MAXNB; bin += 1024) {
            int bc  = sm.b.hist[bin] - sm.b.lbase[bin];   // real count
            int res = (bc + 15) & ~15;
            for (int p = bc; p < res; ++p) {
                int gpos = sm.b.gbase[bin] + p;
                if (gpos < BKT_CAP) bkt[(size_t)bin * BKT_CAP + gpos] = SENT;
            }
        }
    } else {
        // ===== linear: tmp(fp16) = feat @ W, UNSCALED =====
        if (tid < 1024) ((float4*)sm.l.w)[tid] = ((const float4*)weight)[tid];
        __syncthreads();

        int q  = tid >> 3;                  // 0..127 row-quads
        int cg = tid & 7;                   // col group of 4
        int row0 = sub * 512 + q * 4;
        if (row0 >= n_nodes) return;
        int rmax = n_nodes - row0;
        if (rmax > 4) rmax = 4;

        const float4* feat4 = (const float4*)feat;
        float4 acc[4];
#pragma unroll
        for (int r = 0; r < 4; ++r) acc[r] = make_float4(0.f, 0.f, 0.f, 0.f);

        for (int k4 = 0; k4 < IN_F / 4; ++k4) {
            float4 wv0 = *(const float4*)&sm.l.w[(4 * k4 + 0) * OUT_F + 4 * cg];
            float4 wv1 = *(const float4*)&sm.l.w[(4 * k4 + 1) * OUT_F + 4 * cg];
            float4 wv2 = *(const float4*)&sm.l.w[(4 * k4 + 2) * OUT_F + 4 * cg];
            float4 wv3 = *(const float4*)&sm.l.w[(4 * k4 + 3) * OUT_F + 4 * cg];
#pragma unroll
            for (int r = 0; r < 4; ++r) {
                int rr = (r < rmax) ? r : 0;
                float4 f = feat4[(size_t)(row0 + rr) * (IN_F / 4) + k4];
                acc[r].x += f.x * wv0.x + f.y * wv1.x + f.z * wv2.x + f.w * wv3.x;
                acc[r].y += f.x * wv0.y + f.y * wv1.y + f.z * wv2.y + f.w * wv3.y;
                acc[r].z += f.x * wv0.z + f.y * wv1.z + f.z * wv2.z + f.w * wv3.z;
                acc[r].w += f.x * wv0.w + f.y * wv1.w + f.z * wv2.w + f.w * wv3.w;
            }
        }

#pragma unroll
        for (int r = 0; r < 4; ++r) {
            if (r < rmax) {
                union { __half h[4]; uint2 u; } pk;
                pk.h[0] = __float2half(acc[r].x);
                pk.h[1] = __float2half(acc[r].y);
                pk.h[2] = __float2half(acc[r].z);
                pk.h[3] = __float2half(acc[r].w);
                *(uint2*)&tmp[(size_t)(row0 + r) * OUT_F + 4 * cg] = pk.u;
            }
        }
    }
}

// ---------------------------------------------------------------------------
// Fold src-degree scale into tmp in-place (runs after mega, out_cnt final).
// Removes 1.6M random out_cnt loads + 51M redundant rsqrts from the gather.
// 4 threads/row, 16B each; one extra fp16 rounding (error << threshold).
// ---------------------------------------------------------------------------
__global__ __launch_bounds__(256) void scale_tmp(__half* __restrict__ tmp,
                                                 const int* __restrict__ out_cnt,
                                                 int n_nodes) {
    int t = blockIdx.x * 256 + threadIdx.x;
    int node = t >> 2;
    if (node >= n_nodes) return;
    float sc = rsqrtf(fmaxf((float)out_cnt[node], 1.0f));
    uint4* p = (uint4*)(tmp + (size_t)node * OUT_F) + (t & 3);
    uint4 v = *p;
    __half2* h = (__half2*)&v;
#pragma unroll
    for (int i = 0; i < 4; ++i) {
        float2 f = __half22float2(h[i]);
        f.x *= sc; f.y *= sc;
        h[i] = __float22half2_rn(f);
    }
    *p = v;
}

// ---------------------------------------------------------------------------
// Fused sort+gather+overflow: one 1024-thread block per 256-node bucket.
// Sentinel pads skipped in histogram/reorder. Gather inner loop is now pure
// pre-scaled-row load + fp32 add, 8-way ILP, no atomics (round-6 lesson).
// ---------------------------------------------------------------------------
__global__ __launch_bounds__(1024) void sortgather_kernel(
    const unsigned* __restrict__ bkt, const int* __restrict__ gcur,
    const int* __restrict__ in_cnt,
    const int* __restrict__ ovf, const int* __restrict__ ovf_cnt,
    const __half* __restrict__ tmp, float* __restrict__ out, int n_nodes) {

    __shared__ unsigned ent[BKT_CAP];   // 28 KB
    __shared__ unsigned srt[BKT_CAP];   // 28 KB (src ids, node-sorted)
    __shared__ int hist[R_NODES];
    __shared__ int base[R_NODES];
    __shared__ int start[R_NODES];

    int b = blockIdx.x, tid = threadIdx.x;
    int ecnt = min(gcur[b], BKT_CAP);
    const unsigned* gb = bkt + (size_t)b * BKT_CAP;

    if (tid < R_NODES) hist[tid] = 0;
    __syncthreads();

    for (int i = tid; i < ecnt; i += 1024) {
        unsigned v = gb[i];
        ent[i] = v;
        if (v != SENT) atomicAdd(&hist[v & RMASK], 1);
    }
    __syncthreads();

    if (tid < 64) {                      // scan 256 bins, 4/lane
        int a0 = hist[4 * tid], a1 = hist[4 * tid + 1];
        int a2 = hist[4 * tid + 2], a3 = hist[4 * tid + 3];
        int s = a0 + a1 + a2 + a3;
        int sc = s;
        for (int off = 1; off < 64; off <<= 1) {
            int v = __shfl_up(sc, off, 64);
            if (tid >= off) sc += v;
        }
        int excl = sc - s;
        base[4 * tid]     = excl;
        base[4 * tid + 1] = excl + a0;
        base[4 * tid + 2] = excl + a0 + a1;
        base[4 * tid + 3] = excl + a0 + a1 + a2;
    }
    __syncthreads();
    if (tid < R_NODES) start[tid] = base[tid];
    __syncthreads();

    for (int i = tid; i < ecnt; i += 1024) {
        unsigned v = ent[i];
        if (v != SENT) {
            int p = atomicAdd(&base[v & RMASK], 1);
            srt[p] = v >> RSHIFT;        // src only
        }
    }
    __syncthreads();

    int g = tid >> 5;                    // group 0..31
    int c = tid & 31;                    // column
    int n0 = b * R_NODES;
    int novf = min(*ovf_cnt, OVF_CAP);

    for (int ln = g; ln < R_NODES; ln += 32) {
        int node = n0 + ln;
        if (node >= n_nodes) continue;
        int cnt = hist[ln];
        int st  = start[ln];

        float a0 = 0.f, a1 = 0.f, a2 = 0.f, a3 = 0.f;
        int j = 0;
        for (; j + 8 <= cnt; j += 8) {
            int s0 = (int)srt[st + j + 0], s1 = (int)srt[st + j + 1];
            int s2 = (int)srt[st + j + 2], s3 = (int)srt[st + j + 3];
            int s4 = (int)srt[st + j + 4], s5 = (int)srt[st + j + 5];
            int s6 = (int)srt[st + j + 6], s7 = (int)srt[st + j + 7];
            a0 += __half2float(tmp[(size_t)s0 * OUT_F + c]);
            a1 += __half2float(tmp[(size_t)s1 * OUT_F + c]);
            a2 += __half2float(tmp[(size_t)s2 * OUT_F + c]);
            a3 += __half2float(tmp[(size_t)s3 * OUT_F + c]);
            a0 += __half2float(tmp[(size_t)s4 * OUT_F + c]);
            a1 += __half2float(tmp[(size_t)s5 * OUT_F + c]);
            a2 += __half2float(tmp[(size_t)s6 * OUT_F + c]);
            a3 += __half2float(tmp[(size_t)s7 * OUT_F + c]);
        }
        for (; j < cnt; ++j) {
            int s = (int)srt[st + j];
            a0 += __half2float(tmp[(size_t)s * OUT_F + c]);
        }
        for (int e2 = 0; e2 < novf; ++e2) {        // ~always empty
            if (ovf[2 * e2 + 1] == node)
                a0 += __half2float(tmp[(size_t)ovf[2 * e2] * OUT_F + c]);
        }

        float dg = (float)(cnt + in_cnt[node]);
        float sc = rsqrtf(fmaxf(dg, 1.0f));
        out[(size_t)node * OUT_F + c] = (a0 + a1 + a2 + a3) * sc;
    }
}

// ---------------------------------------------------------------------------
// Fallback path (ws too small): degree + scaled-linear + atomic scatter.
// ---------------------------------------------------------------------------
__global__ void degree_kernel(const int* __restrict__ src, const int* __restrict__ dst,
                              int* __restrict__ out_cnt, int* __restrict__ in_cnt,
                              int n_edges) {
    int i = blockIdx.x * blockDim.x + threadIdx.x;
    if (i < n_edges) {
        atomicAdd(&out_cnt[src[i]], 1);
        atomicAdd(&in_cnt[dst[i]], 1);
    }
}

__global__ __launch_bounds__(256) void linear_fb(const float* __restrict__ feat,
                                                 const float* __restrict__ weight,
                                                 const int* __restrict__ out_cnt,
                                                 __half* __restrict__ tmp, int n_nodes) {
    __shared__ float w[IN_F * OUT_F];
    {
        const float4* wg = (const float4*)weight;
        float4* wsh = (float4*)w;
        for (int i = threadIdx.x; i < IN_F * OUT_F / 4; i += 256) wsh[i] = wg[i];
    }
    __syncthreads();
    int q  = threadIdx.x >> 3;
    int cg = threadIdx.x & 7;
    int row0 = blockIdx.x * 128 + q * 4;
    if (row0 >= n_nodes) return;
    int rmax = n_nodes - row0;
    if (rmax > 4) rmax = 4;
    const float4* feat4 = (const float4*)feat;
    float4 acc[4];
#pragma unroll
    for (int r = 0; r < 4; ++r) acc[r] = make_float4(0.f, 0.f, 0.f, 0.f);
    for (int k4 = 0; k4 < IN_F / 4; ++k4) {
        float4 wv0 = *(const float4*)&w[(4 * k4 + 0) * OUT_F + 4 * cg];
        float4 wv1 = *(const float4*)&w[(4 * k4 + 1) * OUT_F + 4 * cg];
        float4 wv2 = *(const float4*)&w[(4 * k4 + 2) * OUT_F + 4 * cg];
        float4 wv3 = *(const float4*)&w[(4 * k4 + 3) * OUT_F + 4 * cg];
#pragma unroll
        for (int r = 0; r < 4; ++r) {
            int rr = (r < rmax) ? r : 0;
            float4 f = feat4[(size_t)(row0 + rr) * (IN_F / 4) + k4];
            acc[r].x += f.x * wv0.x + f.y * wv1.x + f.z * wv2.x + f.w * wv3.x;
            acc[r].y += f.x * wv0.y + f.y * wv1.y + f.z * wv2.y + f.w * wv3.y;
            acc[r].z += f.x * wv0.z + f.y * wv1.z + f.z * wv2.z + f.w * wv3.z;
            acc[r].w += f.x * wv0.w + f.y * wv1.w + f.z * wv2.w + f.w * wv3.w;
        }
    }
#pragma unroll
    for (int r = 0; r < 4; ++r) {
        if (r < rmax) {
            float sc = rsqrtf(fmaxf((float)out_cnt[row0 + r], 1.0f));
            union { __half h[4]; uint2 u; } pk;
            pk.h[0] = __float2half(acc[r].x * sc);
            pk.h[1] = __float2half(acc[r].y * sc);
            pk.h[2] = __float2half(acc[r].z * sc);
            pk.h[3] = __float2half(acc[r].w * sc);
            *(uint2*)&tmp[(size_t)(row0 + r) * OUT_F + 4 * cg] = pk.u;
        }
    }
}

__global__ void scatter_kernel(const int* __restrict__ src, const int* __restrict__ dst,
                               const __half* __restrict__ tmp, float* __restrict__ out,
                               int n_edges) {
    long long t = (long long)blockIdx.x * blockDim.x + threadIdx.x;
    int e = (int)(t >> 5);
    int c = (int)(t & (OUT_F - 1));
    if (e < n_edges) {
        atomicAdd(&out[(size_t)dst[e] * OUT_F + c],
                  __half2float(tmp[(size_t)src[e] * OUT_F + c]));
    }
}

__global__ void finalize_kernel(float* __restrict__ out, const int* __restrict__ in_cnt,
                                int n_total) {
    int t = blockIdx.x * blockDim.x + threadIdx.x;
    if (t < n_total) {
        out[t] *= rsqrtf(fmaxf((float)in_cnt[t >> 5], 1.0f));
    }
}

extern "C" void kernel_launch(void* const* d_in, const int* in_sizes, int n_in,
                              void* d_out, int out_size, void* d_ws, size_t ws_size,
                              hipStream_t stream) {
    const float* feat   = (const float*)d_in[0];
    const int*   src    = (const int*)d_in[1];
    const int*   dst    = (const int*)d_in[2];
    const float* weight = (const float*)d_in[3];
    float*       out    = (float*)d_out;

    int n_nodes = in_sizes[0] / IN_F;   // 100000
    int n_edges = in_sizes[1];          // 1600000
    int n_buckets = (n_nodes + R_NODES - 1) / R_NODES;  // 391 (<= MAXNB)

    // ws layout: [out_cnt n][in_cnt n][gcur MAXNB][ovf_cnt 8][ovf 2*CAP]
    //            [bkt nb*BKT_CAP][tmp fp16 n*32]
    int*      out_cnt = (int*)d_ws;
    int*      in_cnt  = out_cnt + n_nodes;
    int*      gcur    = in_cnt + n_nodes;
    int*      ovf_cnt = gcur + MAXNB;
    int*      ovf     = ovf_cnt + 8;
    unsigned* bkt     = (unsigned*)(ovf + 2 * OVF_CAP);
    __half*   tmp     = (__half*)(bkt + (size_t)n_buckets * BKT_CAP);
    size_t    needed  = (char*)(tmp + (size_t)n_nodes * OUT_F) - (char*)d_ws;

    if (ws_size >= needed && n_buckets <= MAXNB) {
        hipMemsetAsync(out_cnt, 0, ((size_t)2 * n_nodes + MAXNB + 8) * sizeof(int), stream);
        int n_bbl = (n_edges + EPB - 1) / EPB;          // 196
        int n_lbl = (n_nodes + 511) / 512;              // 196
        mega_kernel<<<n_bbl + n_lbl, 1024, 0, stream>>>(
            src, dst, feat, weight, out_cnt, in_cnt, gcur, bkt, ovf, ovf_cnt,
            tmp, n_edges, n_nodes, n_bbl, n_lbl);
        scale_tmp<<<(n_nodes * 4 + 255) / 256, 256, 0, stream>>>(tmp, out_cnt, n_nodes);
        sortgather_kernel<<<n_buckets, 1024, 0, stream>>>(
            bkt, gcur, in_cnt, ovf, ovf_cnt, tmp, out, n_nodes);
    } else {
        // fallback: atomic scatter
        __half* tmp_fb = (__half*)(ovf + 2 * OVF_CAP);
        hipMemsetAsync(out_cnt, 0, ((size_t)2 * n_nodes + MAXNB + 8) * sizeof(int), stream);
        hipMemsetAsync(d_out, 0, (size_t)out_size * sizeof(float), stream);
        degree_kernel<<<(n_edges + 255) / 256, 256, 0, stream>>>(src, dst, out_cnt, in_cnt, n_edges);
        linear_fb<<<(n_nodes + 127) / 128, 256, 0, stream>>>(feat, weight, out_cnt, tmp_fb, n_nodes);
        long long st = (long long)n_edges * OUT_F;
        scatter_kernel<<<(int)((st + 255) / 256), 256, 0, stream>>>(src, dst, tmp_fb, out, n_edges);
        finalize_kernel<<<(n_nodes * OUT_F + 255) / 256, 256, 0, stream>>>(out, in_cnt, n_nodes * OUT_F);
    }
}